// Round 21
// baseline (160.270 us; speedup 1.0000x reference)
//
#include <hip/hip_runtime.h>
#include <hip/hip_bf16.h>

// ---------------------------------------------------------------------------
// PhiLayer: gate-MLP blend + MHA + out-proj, bf16 MFMA pipeline.
// B=2, S=2048, D=1024, H=16, HD=64, GATE_HID=256. M = B*S = 4096.
// ---------------------------------------------------------------------------

typedef __attribute__((ext_vector_type(4))) unsigned int u32x4;
typedef __attribute__((ext_vector_type(2))) unsigned int u32x2;
typedef __attribute__((ext_vector_type(8))) short s16x8;
typedef __attribute__((ext_vector_type(8))) unsigned short u16x8;
typedef __attribute__((ext_vector_type(4))) unsigned short u16x4;
typedef __attribute__((ext_vector_type(4))) float f32x4;

#define QSCALE 0.18033688011112043f   // 0.125 * log2(e): softmax in exp2 domain
#define FIXED_M 24.0f                 // fixed softmax offset (exp2 domain); exact
                                      // for any M absent over/underflow.

// round-to-nearest (ties away) fp32 -> bf16: 2 VALU insts
__device__ __forceinline__ unsigned short f2bf(float f) {
    unsigned int i = __builtin_bit_cast(unsigned int, f) + 0x8000u;
    return (unsigned short)(i >> 16);
}
// pack two fp32 into one u32 of 2 bf16 (lo = a, hi = b): 2 adds + 1 v_perm
__device__ __forceinline__ unsigned int pack2bf(float a, float b) {
    unsigned int ia = __builtin_bit_cast(unsigned int, a) + 0x8000u;
    unsigned int ib = __builtin_bit_cast(unsigned int, b) + 0x8000u;
    return __builtin_amdgcn_perm(ib, ia, 0x07060302u);  // [ib.b3 ib.b2 ia.b3 ia.b2]
}

// async global->LDS, 16B per lane; LDS dest = wave-uniform base + lane*16
__device__ __forceinline__ void gload16(const void* g, void* l) {
    __builtin_amdgcn_global_load_lds(
        (const __attribute__((address_space(1))) void*)g,
        (__attribute__((address_space(3))) void*)l, 16, 0, 0);
}

// ---------------------------------------------------------------------------
// Fused prep: 6 weight transposes (fp32 KxN -> bf16 NxK, 64k x 32n tiles,
// 16B stores) + bias concat.
// 1D grid: [0,3072) transpose (512 blocks/entry), tail 12 blocks bias.
// ---------------------------------------------------------------------------
struct TEntry { const float* src; unsigned short* dst; int K; int N; };
struct TTable { TEntry e[6]; };

__global__ __launch_bounds__(256) void prep_all(
    TTable tt,
    const float* __restrict__ bq, const float* __restrict__ bk,
    const float* __restrict__ bv, float* __restrict__ bqkv)
{
    const int bid = (int)blockIdx.x;
    const int tid = threadIdx.x;
    if (bid < 3072) {
        const TEntry E = tt.e[bid >> 9];
        const int bx = bid & 511;
        const int ntn = E.N >> 5;
        if (bx >= (E.K >> 6) * ntn) return;
        const int n0 = (bx % ntn) * 32, k0 = (bx / ntn) * 64;
        __shared__ float tile[64][33];
        const int lnn = tid & 31, lkk = tid >> 5;    // lkk 0..7
#pragma unroll
        for (int i = 0; i < 8; ++i)
            tile[lkk + i * 8][lnn] = E.src[(size_t)(k0 + lkk + i * 8) * E.N + n0 + lnn];
        __syncthreads();
        const int snn = tid >> 3, skk = (tid & 7) * 8;   // snn 0..31
        u16x8 o;
#pragma unroll
        for (int j = 0; j < 8; ++j) o[j] = f2bf(tile[skk + j][snn]);
        *reinterpret_cast<u16x8*>(&E.dst[(size_t)(n0 + snn) * E.K + k0 + skk]) = o;
        return;
    }
    const int i = (bid - 3072) * 256 + tid;
    if (i < 1024) bqkv[i] = bq[i];
    else if (i < 2048) bqkv[i] = bk[i - 1024];
    else if (i < 3072) bqkv[i] = bv[i - 2048];
}

// ---------------------------------------------------------------------------
// Tiled bf16 MFMA GEMM, 2-phase double-buffered (round-8 proven config):
//   C = epi(A @ Bt^T + bias);  A: MxK bf16 rm, Bt: NxK bf16 rm.
// BM=BN=128, BK=32; gload_lds 16B staging; 4 waves (2x2), wave = 64x64 out.
// 1D grid with XCD-bijective n-grouping (swzn>0, grid = 8*swzn*mtn).
// ---------------------------------------------------------------------------
enum { EPI_GELU = 1, EPI_BLEND = 2, EPI_F32 = 3, EPI_QKV = 4 };

template <int EPI>
__global__ __launch_bounds__(256, 3) void gemm_kernel(
    const unsigned short* __restrict__ A, int lda,
    const unsigned short* __restrict__ Bt, int ldb,
    const float* __restrict__ bias,
    void* __restrict__ Cv, int ldc, int K,
    const float* __restrict__ hb, const float* __restrict__ xb,
    int swzn, int ntn)
{
    __shared__ unsigned short Alds[2][128 * 32];
    __shared__ unsigned short Blds[2][128 * 32];

    const int tid = threadIdx.x;
    const int lane = tid & 63;
    const int w = tid >> 6;
    const int wr = w >> 1, wc = w & 1;
    int mt, nt;
    if (swzn > 0) {
        const int xcd = (int)blockIdx.x & 7, seq = (int)blockIdx.x >> 3;
        nt = xcd * swzn + seq % swzn;
        mt = seq / swzn;
    } else {
        nt = (int)blockIdx.x % ntn;
        mt = (int)blockIdx.x / ntn;
    }
    const int m0 = mt * 128, n0 = nt * 128;
    const int lrow = lane & 15, lko = (lane >> 4) * 8;

    const int grow = w * 32 + (lane >> 2);
    const int gk8 = (lane & 3) * 8;
    const unsigned short* ga0 = A + (size_t)(m0 + grow) * lda + gk8;
    const unsigned short* ga1 = ga0 + (size_t)16 * lda;
    const unsigned short* gb0 = Bt + (size_t)(n0 + grow) * ldb + gk8;
    const unsigned short* gb1 = gb0 + (size_t)16 * ldb;

    auto stage = [&](int buf, int k0) {
        unsigned short* la = &Alds[buf][w * 1024];
        unsigned short* lb = &Blds[buf][w * 1024];
        gload16(ga0 + k0, la);
        gload16(ga1 + k0, la + 512);
        gload16(gb0 + k0, lb);
        gload16(gb1 + k0, lb + 512);
    };

    f32x4 acc[4][4];
#pragma unroll
    for (int i = 0; i < 4; ++i)
#pragma unroll
        for (int j = 0; j < 4; ++j) acc[i][j] = (f32x4){0.f, 0.f, 0.f, 0.f};

    const int kks = K >> 5;
    stage(0, 0);
    __syncthreads();

    for (int t = 0; t < kks; ++t) {
        const int cur = t & 1;
        if (t + 1 < kks) stage(cur ^ 1, (t + 1) << 5);   // overlap with compute

        s16x8 af[4], bfr[4];
#pragma unroll
        for (int mi = 0; mi < 4; ++mi)
            af[mi] = *reinterpret_cast<const s16x8*>(&Alds[cur][(wr * 64 + mi * 16 + lrow) * 32 + lko]);
#pragma unroll
        for (int ni = 0; ni < 4; ++ni)
            bfr[ni] = *reinterpret_cast<const s16x8*>(&Blds[cur][(wc * 64 + ni * 16 + lrow) * 32 + lko]);
#pragma unroll
        for (int mi = 0; mi < 4; ++mi)
#pragma unroll
            for (int ni = 0; ni < 4; ++ni)
                acc[mi][ni] = __builtin_amdgcn_mfma_f32_16x16x32_bf16(af[mi], bfr[ni], acc[mi][ni], 0, 0, 0);

        __syncthreads();
    }

    const int rbase = m0 + wr * 64;
    const int cbase = n0 + wc * 64;
#pragma unroll
    for (int mi = 0; mi < 4; ++mi) {
#pragma unroll
        for (int j = 0; j < 4; ++j) {
            const int r = rbase + mi * 16 + (lane >> 4) * 4 + j;
#pragma unroll
            for (int ni = 0; ni < 4; ++ni) {
                const int c = cbase + ni * 16 + (lane & 15);
                float v = acc[mi][ni][j] + bias[c];
                if constexpr (EPI == EPI_GELU) {
                    float g = 0.5f * v * (1.f + erff(v * 0.70710678118654752f));
                    ((unsigned short*)Cv)[(size_t)r * ldc + c] = f2bf(g);
                } else if constexpr (EPI == EPI_BLEND) {
                    float gate = 1.f / (1.f + __expf(-v));
                    const size_t o = (size_t)r * ldc + c;
                    float bl = gate * hb[o] + (1.f - gate) * xb[o];
                    ((unsigned short*)Cv)[o] = f2bf(bl);
                } else if constexpr (EPI == EPI_QKV) {
                    const float scl = (c < 1024) ? QSCALE : 1.f;
                    ((unsigned short*)Cv)[(size_t)r * ldc + c] = f2bf(v * scl);
                } else {
                    ((float*)Cv)[(size_t)r * ldc + c] = v;
                }
            }
        }
    }
}

// ---------------------------------------------------------------------------
// 64x64-tile GEMM, templated epilogue, 4 blocks/CU (for N=1024 layers:
// blend + out-proj; grid = 8*swzn*mtn with swzn=2 -> 1024 blocks).
// ---------------------------------------------------------------------------
template <int EPI>
__global__ __launch_bounds__(256, 4) void gemm64_kernel(
    const unsigned short* __restrict__ A, int lda,
    const unsigned short* __restrict__ Bt, int ldb,
    const float* __restrict__ bias,
    void* __restrict__ Cv, int ldc, int K,
    const float* __restrict__ hb, const float* __restrict__ xb,
    int swzn)
{
    __shared__ unsigned short Alds[2][64 * 32];
    __shared__ unsigned short Blds[2][64 * 32];

    const int tid = threadIdx.x;
    const int lane = tid & 63;
    const int w = tid >> 6;
    const int wr = w >> 1, wc = w & 1;
    const int xcd = (int)blockIdx.x & 7, seq = (int)blockIdx.x >> 3;
    const int nt = xcd * swzn + seq % swzn;
    const int mt = seq / swzn;
    const int m0 = mt * 64, n0 = nt * 64;
    const int lrow = lane & 15, lko = (lane >> 4) * 8;

    const int grow = w * 16 + (lane >> 2);
    const int gk8 = (lane & 3) * 8;
    const unsigned short* ga = A + (size_t)(m0 + grow) * lda + gk8;
    const unsigned short* gb = Bt + (size_t)(n0 + grow) * ldb + gk8;

    auto stage = [&](int buf, int k0) {
        gload16(ga + k0, &Alds[buf][w * 512]);
        gload16(gb + k0, &Blds[buf][w * 512]);
    };

    f32x4 acc[2][2];
#pragma unroll
    for (int i = 0; i < 2; ++i)
#pragma unroll
        for (int j = 0; j < 2; ++j) acc[i][j] = (f32x4){0.f, 0.f, 0.f, 0.f};

    const int kks = K >> 5;
    stage(0, 0);
    __syncthreads();

    for (int t = 0; t < kks; ++t) {
        const int cur = t & 1;
        if (t + 1 < kks) stage(cur ^ 1, (t + 1) << 5);

        s16x8 af[2], bfr[2];
#pragma unroll
        for (int mi = 0; mi < 2; ++mi)
            af[mi] = *reinterpret_cast<const s16x8*>(&Alds[cur][(wr * 32 + mi * 16 + lrow) * 32 + lko]);
#pragma unroll
        for (int ni = 0; ni < 2; ++ni)
            bfr[ni] = *reinterpret_cast<const s16x8*>(&Blds[cur][(wc * 32 + ni * 16 + lrow) * 32 + lko]);
#pragma unroll
        for (int mi = 0; mi < 2; ++mi)
#pragma unroll
            for (int ni = 0; ni < 2; ++ni)
                acc[mi][ni] = __builtin_amdgcn_mfma_f32_16x16x32_bf16(af[mi], bfr[ni], acc[mi][ni], 0, 0, 0);

        __syncthreads();
    }

    const int rbase = m0 + wr * 32;
    const int cbase = n0 + wc * 32;
#pragma unroll
    for (int mi = 0; mi < 2; ++mi) {
#pragma unroll
        for (int j = 0; j < 4; ++j) {
            const int r = rbase + mi * 16 + (lane >> 4) * 4 + j;
#pragma unroll
            for (int ni = 0; ni < 2; ++ni) {
                const int c = cbase + ni * 16 + (lane & 15);
                float v = acc[mi][ni][j] + bias[c];
                if constexpr (EPI == EPI_BLEND) {
                    float gate = 1.f / (1.f + __expf(-v));
                    const size_t o = (size_t)r * ldc + c;
                    float bl = gate * hb[o] + (1.f - gate) * xb[o];
                    ((unsigned short*)Cv)[o] = f2bf(bl);
                } else {
                    ((float*)Cv)[(size_t)r * ldc + c] = v;
                }
            }
        }
    }
}

// ---------------------------------------------------------------------------
// V GEMM with fused head-transpose epilogue (replaces QKV's V third +
// transpose_v):  V = blend @ Wv^T + bv, written directly as
// vt[bh=(b*16+h)][d][s]. 64x64 tiles; nt = head h (0..15), mt = row-tile
// (0..63); tile never straddles the batch boundary (2048 % 64 == 0).
// Epilogue: bf16 C-tile -> LDS [64][72] -> barrier -> column reads
// (64 lanes x consecutive d = conflict-free) -> coalesced 16B stores along s.
// grid = 8 xcd * 2 swz * 64 mt = 1024 blocks = 4 blocks/CU.
// ---------------------------------------------------------------------------
__global__ __launch_bounds__(256, 4) void gemm_vt(
    const unsigned short* __restrict__ A,    // blend [4096][1024]
    const unsigned short* __restrict__ Bt,   // wqkvT + 2048*1024 (V rows)
    const float* __restrict__ bias,          // bqkv + 2048
    unsigned short* __restrict__ vt)         // [32][64][2048]
{
    __shared__ unsigned short Alds[2][64 * 32];
    __shared__ unsigned short Blds[2][64 * 32];
    __shared__ unsigned short Clds[64][72];

    const int tid = threadIdx.x;
    const int lane = tid & 63;
    const int w = tid >> 6;
    const int wr = w >> 1, wc = w & 1;
    const int xcd = (int)blockIdx.x & 7, seq = (int)blockIdx.x >> 3;
    const int nt = xcd * 2 + (seq & 1);      // head 0..15
    const int mt = seq >> 1;                 // row-tile 0..63
    const int m0 = mt * 64, n0 = nt * 64;
    const int lrow = lane & 15, lko = (lane >> 4) * 8;

    const int grow = w * 16 + (lane >> 2);
    const int gk8 = (lane & 3) * 8;
    const unsigned short* ga = A + (size_t)(m0 + grow) * 1024 + gk8;
    const unsigned short* gb = Bt + (size_t)(n0 + grow) * 1024 + gk8;

    auto stage = [&](int buf, int k0) {
        gload16(ga + k0, &Alds[buf][w * 512]);
        gload16(gb + k0, &Blds[buf][w * 512]);
    };

    f32x4 acc[2][2];
#pragma unroll
    for (int i = 0; i < 2; ++i)
#pragma unroll
        for (int j = 0; j < 2; ++j) acc[i][j] = (f32x4){0.f, 0.f, 0.f, 0.f};

    stage(0, 0);
    __syncthreads();

    for (int t = 0; t < 32; ++t) {
        const int cur = t & 1;
        if (t + 1 < 32) stage(cur ^ 1, (t + 1) << 5);

        s16x8 af[2], bfr[2];
#pragma unroll
        for (int mi = 0; mi < 2; ++mi)
            af[mi] = *reinterpret_cast<const s16x8*>(&Alds[cur][(wr * 32 + mi * 16 + lrow) * 32 + lko]);
#pragma unroll
        for (int ni = 0; ni < 2; ++ni)
            bfr[ni] = *reinterpret_cast<const s16x8*>(&Blds[cur][(wc * 32 + ni * 16 + lrow) * 32 + lko]);
#pragma unroll
        for (int mi = 0; mi < 2; ++mi)
#pragma unroll
            for (int ni = 0; ni < 2; ++ni)
                acc[mi][ni] = __builtin_amdgcn_mfma_f32_16x16x32_bf16(af[mi], bfr[ni], acc[mi][ni], 0, 0, 0);

        __syncthreads();
    }

    // C tile (bf16, bias added) -> LDS
#pragma unroll
    for (int mi = 0; mi < 2; ++mi) {
#pragma unroll
        for (int j = 0; j < 4; ++j) {
            const int rl = wr * 32 + mi * 16 + (lane >> 4) * 4 + j;
#pragma unroll
            for (int ni = 0; ni < 2; ++ni) {
                const int cl = wc * 32 + ni * 16 + (lane & 15);
                Clds[rl][cl] = f2bf(acc[mi][ni][j] + bias[n0 + cl]);
            }
        }
    }
    __syncthreads();

    // transposed write: thread -> (d = tid&63, s-chunk = tid>>6)
    const int b = m0 >> 11, s0 = m0 & 2047;
    const int d = tid & 63, ch = tid >> 6;
    u16x8 o0, o1;
#pragma unroll
    for (int i = 0; i < 8; ++i) o0[i] = Clds[ch * 16 + i][d];
#pragma unroll
    for (int i = 0; i < 8; ++i) o1[i] = Clds[ch * 16 + 8 + i][d];
    unsigned short* dst = vt + ((size_t)((b * 16 + nt) * 64 + d)) * 2048 + s0 + ch * 16;
    *reinterpret_cast<u16x8*>(dst) = o0;
    *reinterpret_cast<u16x8*>(dst + 8) = o1;
}

// ---------------------------------------------------------------------------
// Gate-1 split-K partial GEMM: partial[ks] = hx[:, ks*512:+512] @ Wg1-slice.
// BM=32, BN=256 (full N -> A read ONCE), KS=4; grid = 512 = 2 blocks/CU.
// ---------------------------------------------------------------------------
__global__ __launch_bounds__(256, 4) void gelu_partial(
    const float* __restrict__ h, const float* __restrict__ x,
    const unsigned short* __restrict__ Bt,   // wg1T [256][2048]
    float* __restrict__ partial)             // [4][4096][256]
{
    __shared__ unsigned short Alds[2][32 * 32];
    __shared__ unsigned short Blds[2][256 * 32];

    const int tid = threadIdx.x;
    const int lane = tid & 63;
    const int w = tid >> 6;
    const int mt = (int)blockIdx.x >> 2, ks = (int)blockIdx.x & 3;
    const int m0 = mt * 32, kbase = ks * 512;
    const int lrow = lane & 15, lko = (lane >> 4) * 8;

    const int arl = tid >> 3, ac4 = (tid & 7) * 4;
    const size_t arg = (size_t)(m0 + arl) * 1024;
    auto loadA = [&](int k0, f32x4& v) {
        v = *reinterpret_cast<const f32x4*>((k0 < 1024 ? h : x) + arg + (k0 & 1023) + ac4);
    };
    auto writeA = [&](int buf, const f32x4& v) {
        u32x2 p = {pack2bf(v[0], v[1]), pack2bf(v[2], v[3])};
        *reinterpret_cast<u32x2*>(&Alds[buf][arl * 32 + ac4]) = p;
    };

    const int brow = w * 64 + (lane >> 2);
    const int bk8 = (lane & 3) * 8;
    const unsigned short* gb = Bt + (size_t)brow * 2048 + kbase + bk8;
    auto stageB = [&](int buf, int k0) {
#pragma unroll
        for (int i = 0; i < 4; ++i)
            gload16(gb + (size_t)(i * 16) * 2048 + k0, &Blds[buf][(w * 64 + i * 16) * 32]);
    };

    f32x4 acc[2][4];
#pragma unroll
    for (int i = 0; i < 2; ++i)
#pragma unroll
        for (int j = 0; j < 4; ++j) acc[i][j] = (f32x4){0.f, 0.f, 0.f, 0.f};

    f32x4 areg;
    loadA(kbase, areg);
    stageB(0, 0);
    writeA(0, areg);
    __syncthreads();

    for (int t = 0; t < 16; ++t) {
        const int cur = t & 1;
        if (t + 1 < 16) {
            loadA(kbase + ((t + 1) << 5), areg);   // issue early (T14)
            stageB(cur ^ 1, (t + 1) << 5);
        }

        s16x8 af[2], bfr[4];
#pragma unroll
        for (int mi = 0; mi < 2; ++mi)
            af[mi] = *reinterpret_cast<const s16x8*>(&Alds[cur][(mi * 16 + lrow) * 32 + lko]);
#pragma unroll
        for (int ni = 0; ni < 4; ++ni)
            bfr[ni] = *reinterpret_cast<const s16x8*>(&Blds[cur][(w * 64 + ni * 16 + lrow) * 32 + lko]);
#pragma unroll
        for (int mi = 0; mi < 2; ++mi)
#pragma unroll
            for (int ni = 0; ni < 4; ++ni)
                acc[mi][ni] = __builtin_amdgcn_mfma_f32_16x16x32_bf16(af[mi], bfr[ni], acc[mi][ni], 0, 0, 0);

        if (t + 1 < 16) writeA(cur ^ 1, areg);     // write late (T14)
        __syncthreads();
    }

    float* pbase = partial + (size_t)ks * 4096 * 256;
#pragma unroll
    for (int mi = 0; mi < 2; ++mi) {
#pragma unroll
        for (int j = 0; j < 4; ++j) {
            const int r = m0 + mi * 16 + (lane >> 4) * 4 + j;
#pragma unroll
            for (int ni = 0; ni < 4; ++ni) {
                const int c = w * 64 + ni * 16 + (lane & 15);
                pbase[(size_t)r * 256 + c] = acc[mi][ni][j];
            }
        }
    }
}

// ---------------------------------------------------------------------------
// Gate-1 reduce: g1 = bf16(gelu(sum_ks partial + bias)). 4 elems/thread.
// ---------------------------------------------------------------------------
__global__ __launch_bounds__(256) void gelu_reduce(
    const float* __restrict__ partial, const float* __restrict__ bias,
    unsigned short* __restrict__ g1)
{
    const size_t idx = ((size_t)blockIdx.x * 256 + threadIdx.x) * 4;
    const int c = (int)(idx & 255);
    f32x4 s = *reinterpret_cast<const f32x4*>(partial + idx);
#pragma unroll
    for (int ks = 1; ks < 4; ++ks) {
        f32x4 p = *reinterpret_cast<const f32x4*>(partial + (size_t)ks * 4096 * 256 + idx);
        s[0] += p[0]; s[1] += p[1]; s[2] += p[2]; s[3] += p[3];
    }
    f32x4 bb = *reinterpret_cast<const f32x4*>(bias + c);
    u16x4 o;
#pragma unroll
    for (int j = 0; j < 4; ++j) {
        float v = s[j] + bb[j];
        o[j] = f2bf(0.5f * v * (1.f + erff(v * 0.70710678118654752f)));
    }
    *reinterpret_cast<u16x4*>(g1 + idx) = o;
}

// ---------------------------------------------------------------------------
// Flash attention (round-18 proven): swapped-operand, QBLK=128, 4 waves x 32
// q-rows, grid 512. K/V via global_load_lds with both-sides XOR chunk-swizzle:
//   LDS[R][C] = orig[R][C ^ (R&7)]  (C = 16B chunk index 0..7)
// FULLY ROTATED PV: both PV clusters of tile t execute at the TOP of
// iteration t+1. -M folded into the QK accumulator init. setprio(1) around
// MFMA clusters. FIXED-M softmax.
//   qk : [4096][2048] bf16 (q pre-scaled by 0.125*log2e | k)
//   vt : [32 bh][64 d][2048 s] bf16
//   out: [4096][1024] bf16
// 1D XCD-grouped grid: 512 blocks = 8 xcd x (4 bh x 16 qt).
// ---------------------------------------------------------------------------
#define ALD 72   // Plds row stride only

__global__ __launch_bounds__(256, 3) void attn_kernel(
    const unsigned short* __restrict__ qk,
    const unsigned short* __restrict__ vt,
    unsigned short* __restrict__ out)
{
    __shared__ unsigned short Klds[2][64 * 64];   // linear 128B rows
    __shared__ unsigned short Vlds[2][64 * 64];
    __shared__ unsigned short Plds[2][4][16 * ALD];   // [P-group][wave]

    const int tid = threadIdx.x, lane = tid & 63, w = tid >> 6;   // w 0..3
    const int xcd = (int)blockIdx.x & 7, seq = (int)blockIdx.x >> 3;  // 512 = 8*64
    const int bh = xcd * 4 + (seq & 3);   // 4 heads per XCD
    const int qt = seq >> 2;              // 0..15
    const int b = bh >> 4, h = bh & 15;
    const int rb = b * 2048;
    const int lrow = lane & 15, g = lane >> 4, lko = g * 8;

    s16x8 qf[2][2];
#pragma unroll
    for (int qg = 0; qg < 2; ++qg) {
        const size_t qrow = (size_t)(rb + qt * 128 + w * 32 + qg * 16 + lrow) * 2048 + h * 64;
        qf[qg][0] = *reinterpret_cast<const s16x8*>(qk + qrow + lko);
        qf[qg][1] = *reinterpret_cast<const s16x8*>(qk + qrow + 32 + lko);
    }

    const int grow = w * 16 + (lane >> 3);
    const int gswz = ((lane & 7) ^ (lane >> 3)) * 8;   // elems
    const unsigned short* kgp = qk + (size_t)(rb + grow) * 2048 + 1024 + h * 64 + gswz;
    const unsigned short* vgp = vt + (size_t)(bh * 64 + grow) * 2048 + gswz;

    auto stage = [&](int buf, int t0) {
        gload16(kgp + (size_t)t0 * 2048, &Klds[buf][w * 1024]);
        gload16(kgp + (size_t)(t0 + 8) * 2048, &Klds[buf][w * 1024 + 512]);
        gload16(vgp + t0, &Vlds[buf][w * 1024]);
        gload16(vgp + t0 + 8 * 2048, &Vlds[buf][w * 1024 + 512]);
    };

    const int cs0 = ((g) ^ (lrow & 7)) * 8;
    const int cs1 = ((4 + g) ^ (lrow & 7)) * 8;

    f32x4 acc0[4], acc1[4];
#pragma unroll
    for (int di = 0; di < 4; ++di) {
        acc0[di] = (f32x4){0.f, 0.f, 0.f, 0.f};
        acc1[di] = (f32x4){0.f, 0.f, 0.f, 0.f};
    }
    float lsum0 = 0.f, lsum1 = 0.f;

    unsigned short* pw0 = &Plds[0][w][0];
    unsigned short* pw1 = &Plds[1][w][0];
    s16x8 vf[2][4];   // persists across iterations (PV rotation)

    stage(0, 0);
    __syncthreads();

    for (int t0 = 0; t0 < 2048; t0 += 64) {
        const int cur = (t0 >> 6) & 1;
        if (t0 + 64 < 2048) stage(cur ^ 1, t0 + 64);

        // PV of PREVIOUS tile (both groups)
        if (t0 > 0) {
            __builtin_amdgcn_s_setprio(1);
#pragma unroll
            for (int st = 0; st < 2; ++st) {
                s16x8 pf0 = *reinterpret_cast<const s16x8*>(&pw0[lrow * ALD + st * 32 + lko]);
#pragma unroll
                for (int di = 0; di < 4; ++di)
                    acc0[di] = __builtin_amdgcn_mfma_f32_16x16x32_bf16(vf[st][di], pf0, acc0[di], 0, 0, 0);
            }
#pragma unroll
            for (int st = 0; st < 2; ++st) {
                s16x8 pf1 = *reinterpret_cast<const s16x8*>(&pw1[lrow * ALD + st * 32 + lko]);
#pragma unroll
                for (int di = 0; di < 4; ++di)
                    acc1[di] = __builtin_amdgcn_mfma_f32_16x16x32_bf16(vf[st][di], pf1, acc1[di], 0, 0, 0);
            }
            __builtin_amdgcn_s_setprio(0);
        }

        s16x8 kf[4][2];
#pragma unroll
        for (int ni = 0; ni < 4; ++ni) {
            kf[ni][0] = *reinterpret_cast<const s16x8*>(&Klds[cur][(ni * 16 + lrow) * 64 + cs0]);
            kf[ni][1] = *reinterpret_cast<const s16x8*>(&Klds[cur][(ni * 16 + lrow) * 64 + cs1]);
        }

        // QK group 0 (accumulator pre-seeded with -M)
        f32x4 s0[4];
#pragma unroll
        for (int ni = 0; ni < 4; ++ni)
            s0[ni] = (f32x4){-FIXED_M, -FIXED_M, -FIXED_M, -FIXED_M};
        __builtin_amdgcn_s_setprio(1);
#pragma unroll
        for (int ni = 0; ni < 4; ++ni)
#pragma unroll
            for (int fi = 0; fi < 2; ++fi)
                s0[ni] = __builtin_amdgcn_mfma_f32_16x16x32_bf16(kf[ni][fi], qf[0][fi], s0[ni], 0, 0, 0);
        __builtin_amdgcn_s_setprio(0);

        // P0 = exp2(s0) -> pw0
#pragma unroll
        for (int ni = 0; ni < 4; ++ni) {
            float p0 = __builtin_amdgcn_exp2f(s0[ni][0]);
            float p1 = __builtin_amdgcn_exp2f(s0[ni][1]);
            float p2 = __builtin_amdgcn_exp2f(s0[ni][2]);
            float p3 = __builtin_amdgcn_exp2f(s0[ni][3]);
            lsum0 += (p0 + p1) + (p2 + p3);
            u32x2 pk = {pack2bf(p0, p1), pack2bf(p2, p3)};
            *reinterpret_cast<u32x2*>(&pw0[lrow * ALD + ni * 16 + g * 4]) = pk;
        }

        // QK group 1 (kf reused)
        f32x4 s1[4];
#pragma unroll
        for (int ni = 0; ni < 4; ++ni)
            s1[ni] = (f32x4){-FIXED_M, -FIXED_M, -FIXED_M, -FIXED_M};
        __builtin_amdgcn_s_setprio(1);
#pragma unroll
        for (int ni = 0; ni < 4; ++ni)
#pragma unroll
            for (int fi = 0; fi < 2; ++fi)
                s1[ni] = __builtin_amdgcn_mfma_f32_16x16x32_bf16(kf[ni][fi], qf[1][fi], s1[ni], 0, 0, 0);
        __builtin_amdgcn_s_setprio(0);

        // V fragments for NEXT iteration's PV
#pragma unroll
        for (int di = 0; di < 4; ++di) {
            vf[0][di] = *reinterpret_cast<const s16x8*>(&Vlds[cur][(di * 16 + lrow) * 64 + cs0]);
            vf[1][di] = *reinterpret_cast<const s16x8*>(&Vlds[cur][(di * 16 + lrow) * 64 + cs1]);
        }

        // P1 = exp2(s1) -> pw1
#pragma unroll
        for (int ni = 0; ni < 4; ++ni) {
            float p0 = __builtin_amdgcn_exp2f(s1[ni][0]);
            float p1 = __builtin_amdgcn_exp2f(s1[ni][1]);
            float p2 = __builtin_amdgcn_exp2f(s1[ni][2]);
            float p3 = __builtin_amdgcn_exp2f(s1[ni][3]);
            lsum1 += (p0 + p1) + (p2 + p3);
            u32x2 pk = {pack2bf(p0, p1), pack2bf(p2, p3)};
            *reinterpret_cast<u32x2*>(&pw1[lrow * ALD + ni * 16 + g * 4]) = pk;
        }

        __syncthreads();
    }

    // tail: PV of the last tile (both groups)
#pragma unroll
    for (int st = 0; st < 2; ++st) {
        s16x8 pf0 = *reinterpret_cast<const s16x8*>(&pw0[lrow * ALD + st * 32 + lko]);
#pragma unroll
        for (int di = 0; di < 4; ++di)
            acc0[di] = __builtin_amdgcn_mfma_f32_16x16x32_bf16(vf[st][di], pf0, acc0[di], 0, 0, 0);
    }
#pragma unroll
    for (int st = 0; st < 2; ++st) {
        s16x8 pf1 = *reinterpret_cast<const s16x8*>(&pw1[lrow * ALD + st * 32 + lko]);
#pragma unroll
        for (int di = 0; di < 4; ++di)
            acc1[di] = __builtin_amdgcn_mfma_f32_16x16x32_bf16(vf[st][di], pf1, acc1[di], 0, 0, 0);
    }

    lsum0 += __shfl_xor(lsum0, 16);
    lsum0 += __shfl_xor(lsum0, 32);
    lsum1 += __shfl_xor(lsum1, 16);
    lsum1 += __shfl_xor(lsum1, 32);
    const float inv0 = 1.f / lsum0;
    const float inv1 = 1.f / lsum1;
    const size_t orow0 = (size_t)(rb + qt * 128 + w * 32 + lrow) * 1024 + h * 64;
    const size_t orow1 = orow0 + (size_t)16 * 1024;
#pragma unroll
    for (int di = 0; di < 4; ++di) {
        u32x2 ov0 = {pack2bf(acc0[di][0] * inv0, acc0[di][1] * inv0),
                     pack2bf(acc0[di][2] * inv0, acc0[di][3] * inv0)};
        *reinterpret_cast<u32x2*>(&out[orow0 + di * 16 + g * 4]) = ov0;
        u32x2 ov1 = {pack2bf(acc1[di][0] * inv1, acc1[di][1] * inv1),
                     pack2bf(acc1[di][2] * inv1, acc1[di][3] * inv1)};
        *reinterpret_cast<u32x2*>(&out[orow1 + di * 16 + g * 4]) = ov1;
    }
}

// ---------------------------------------------------------------------------
extern "C" void kernel_launch(void* const* d_in, const int* in_sizes, int n_in,
                              void* d_out, int out_size, void* d_ws, size_t ws_size,
                              hipStream_t stream)
{
    const float* h   = (const float*)d_in[0];
    const float* x   = (const float*)d_in[1];
    const float* Wq  = (const float*)d_in[2];
    const float* bq  = (const float*)d_in[3];
    const float* Wk  = (const float*)d_in[4];
    const float* bk  = (const float*)d_in[5];
    const float* Wv  = (const float*)d_in[6];
    const float* bv  = (const float*)d_in[7];
    const float* Wo  = (const float*)d_in[8];
    const float* bo  = (const float*)d_in[9];
    const float* Wg1 = (const float*)d_in[10];
    const float* bg1 = (const float*)d_in[11];
    const float* Wg2 = (const float*)d_in[12];
    const float* bg2 = (const float*)d_in[13];

    char* ws = (char*)d_ws;
    size_t off = 0;
    auto alloc = [&](size_t bytes) {
        void* p = ws + off;
        off += (bytes + 255) & ~(size_t)255;
        return p;
    };
    unsigned short* wg1T  = (unsigned short*)alloc((size_t)256 * 2048 * 2);
    unsigned short* wg2T  = (unsigned short*)alloc((size_t)1024 * 256 * 2);
    unsigned short* wqkvT = (unsigned short*)alloc((size_t)3072 * 1024 * 2);
    unsigned short* woT   = (unsigned short*)alloc((size_t)1024 * 1024 * 2);
    float*          bqkv  = (float*)alloc((size_t)3072 * 4);
    unsigned short* blend = (unsigned short*)alloc((size_t)4096 * 1024 * 2);
    unsigned short* attno = (unsigned short*)alloc((size_t)4096 * 1024 * 2);
    unsigned short* vtb   = (unsigned short*)alloc((size_t)32 * 64 * 2048 * 2);
    unsigned short* g1    = (unsigned short*)alloc((size_t)4096 * 256 * 2);
    unsigned short* qk    = (unsigned short*)alloc((size_t)4096 * 2048 * 2);
    // gate-1 split-K partials (16 MB fp32) alias the qk buffer (16 MB):
    // partials are dead before the QK GEMM writes qk.
    float* partial = (float*)qk;
    (void)ws_size; (void)in_sizes; (void)n_in; (void)out_size;

    // fused prep: weight transposes + bias concat (one launch)
    TTable tt;
    tt.e[0] = {Wg1, wg1T, 2048, 256};
    tt.e[1] = {Wg2, wg2T, 256, 1024};
    tt.e[2] = {Wq, wqkvT, 1024, 1024};
    tt.e[3] = {Wk, wqkvT + (size_t)1024 * 1024, 1024, 1024};
    tt.e[4] = {Wv, wqkvT + (size_t)2048 * 1024, 1024, 1024};
    tt.e[5] = {Wo, woT, 1024, 1024};
    prep_all<<<3072 + 12, 256, 0, stream>>>(tt, bq, bk, bv, bqkv);

    // gate MLP: split-K gate1 (A read once, 512 blocks) + reduce/GELU
    gelu_partial<<<512, 256, 0, stream>>>(h, x, wg1T, partial);
    gelu_reduce<<<1024, 256, 0, stream>>>(partial, bg1, g1);
    // blend: 64x64 tiles, 1024 blocks = 4 blocks/CU
    gemm64_kernel<EPI_BLEND><<<1024, 256, 0, stream>>>(
        g1, 256, wg2T, 256, bg2, blend, 1024, 256, h, x, 2);

    // Q|K GEMM (N = 2048; q pre-scaled) — overwrites partial (dead)
    gemm_kernel<EPI_QKV><<<512, 256, 0, stream>>>(
        blend, 1024, wqkvT, 1024, bqkv, qk, 2048, 1024, nullptr, nullptr, 2, 16);

    // V GEMM with fused head-transpose epilogue -> vtb
    gemm_vt<<<1024, 256, 0, stream>>>(
        blend, wqkvT + (size_t)2048 * 1024, bqkv + 2048, vtb);

    // attention (XCD-grouped 1D grid, QBLK=128, fully-rotated PV pipeline)
    attn_kernel<<<512, 256, 0, stream>>>(qk, vtb, attno);

    // output projection -> fp32: 64x64 tiles, 1024 blocks = 4 blocks/CU
    gemm64_kernel<EPI_F32><<<1024, 256, 0, stream>>>(
        attno, 1024, woT, 1024, bo, (float*)d_out, 1024, 1024, nullptr, nullptr, 2);
}

// Round 22
// 147.604 us; speedup vs baseline: 1.0858x; 1.0858x over previous
//
#include <hip/hip_runtime.h>
#include <hip/hip_bf16.h>

// ---------------------------------------------------------------------------
// PhiLayer: gate-MLP blend + MHA + out-proj, bf16 MFMA pipeline.
// B=2, S=2048, D=1024, H=16, HD=64, GATE_HID=256. M = B*S = 4096.
// Round-20 proven configuration (147.8 us, benched twice).
// ---------------------------------------------------------------------------

typedef __attribute__((ext_vector_type(4))) unsigned int u32x4;
typedef __attribute__((ext_vector_type(2))) unsigned int u32x2;
typedef __attribute__((ext_vector_type(8))) short s16x8;
typedef __attribute__((ext_vector_type(8))) unsigned short u16x8;
typedef __attribute__((ext_vector_type(4))) unsigned short u16x4;
typedef __attribute__((ext_vector_type(4))) float f32x4;

#define QSCALE 0.18033688011112043f   // 0.125 * log2(e): softmax in exp2 domain
#define FIXED_M 24.0f                 // fixed softmax offset (exp2 domain); exact
                                      // for any M absent over/underflow.

// round-to-nearest (ties away) fp32 -> bf16: 2 VALU insts
__device__ __forceinline__ unsigned short f2bf(float f) {
    unsigned int i = __builtin_bit_cast(unsigned int, f) + 0x8000u;
    return (unsigned short)(i >> 16);
}
// pack two fp32 into one u32 of 2 bf16 (lo = a, hi = b): 2 adds + 1 v_perm
__device__ __forceinline__ unsigned int pack2bf(float a, float b) {
    unsigned int ia = __builtin_bit_cast(unsigned int, a) + 0x8000u;
    unsigned int ib = __builtin_bit_cast(unsigned int, b) + 0x8000u;
    return __builtin_amdgcn_perm(ib, ia, 0x07060302u);  // [ib.b3 ib.b2 ia.b3 ia.b2]
}

// async global->LDS, 16B per lane; LDS dest = wave-uniform base + lane*16
__device__ __forceinline__ void gload16(const void* g, void* l) {
    __builtin_amdgcn_global_load_lds(
        (const __attribute__((address_space(1))) void*)g,
        (__attribute__((address_space(3))) void*)l, 16, 0, 0);
}

// ---------------------------------------------------------------------------
// Fused prep: 6 weight transposes (fp32 KxN -> bf16 NxK, 64k x 32n tiles,
// 16B stores) + bias concat.
// 1D grid: [0,3072) transpose (512 blocks/entry), tail 12 blocks bias.
// ---------------------------------------------------------------------------
struct TEntry { const float* src; unsigned short* dst; int K; int N; };
struct TTable { TEntry e[6]; };

__global__ __launch_bounds__(256) void prep_all(
    TTable tt,
    const float* __restrict__ bq, const float* __restrict__ bk,
    const float* __restrict__ bv, float* __restrict__ bqkv)
{
    const int bid = (int)blockIdx.x;
    const int tid = threadIdx.x;
    if (bid < 3072) {
        const TEntry E = tt.e[bid >> 9];
        const int bx = bid & 511;
        const int ntn = E.N >> 5;
        if (bx >= (E.K >> 6) * ntn) return;
        const int n0 = (bx % ntn) * 32, k0 = (bx / ntn) * 64;
        __shared__ float tile[64][33];
        const int lnn = tid & 31, lkk = tid >> 5;    // lkk 0..7
#pragma unroll
        for (int i = 0; i < 8; ++i)
            tile[lkk + i * 8][lnn] = E.src[(size_t)(k0 + lkk + i * 8) * E.N + n0 + lnn];
        __syncthreads();
        const int snn = tid >> 3, skk = (tid & 7) * 8;   // snn 0..31
        u16x8 o;
#pragma unroll
        for (int j = 0; j < 8; ++j) o[j] = f2bf(tile[skk + j][snn]);
        *reinterpret_cast<u16x8*>(&E.dst[(size_t)(n0 + snn) * E.K + k0 + skk]) = o;
        return;
    }
    const int i = (bid - 3072) * 256 + tid;
    if (i < 1024) bqkv[i] = bq[i];
    else if (i < 2048) bqkv[i] = bk[i - 1024];
    else if (i < 3072) bqkv[i] = bv[i - 2048];
}

// ---------------------------------------------------------------------------
// V transpose per head: qkv [4096][3072] (v at col 2048) -> vt [32][64][2048]
// ---------------------------------------------------------------------------
__global__ __launch_bounds__(256) void transpose_v(
    const unsigned short* __restrict__ qkv, unsigned short* __restrict__ vt)
{
    __shared__ unsigned short t[64][65];
    const int st = blockIdx.x;            // s-tile 0..31
    const int bh = blockIdx.y;            // 0..31
    const int b = bh >> 4, h = bh & 15;
    const int tx = threadIdx.x & 63, ty = threadIdx.x >> 6;   // ty 0..3
    const int s0 = st * 64;
    const size_t base = (size_t)(b * 2048 + s0) * 3072 + 2048 + h * 64;
#pragma unroll
    for (int i = 0; i < 16; ++i)
        t[ty + i * 4][tx] = qkv[base + (size_t)(ty + i * 4) * 3072 + tx];
    __syncthreads();
    const size_t obase = (size_t)(bh * 64) * 2048 + s0;
#pragma unroll
    for (int i = 0; i < 16; ++i)
        vt[obase + (size_t)(ty + i * 4) * 2048 + tx] = t[tx][ty + i * 4];
}

// ---------------------------------------------------------------------------
// Tiled bf16 MFMA GEMM, 2-phase double-buffered (round-8 proven config):
//   C = epi(A @ Bt^T + bias);  A: MxK bf16 rm, Bt: NxK bf16 rm.
// BM=BN=128, BK=32; gload_lds 16B staging; 4 waves (2x2), wave = 64x64 out.
// 1D grid with XCD-bijective n-grouping (swzn>0, grid = 8*swzn*mtn).
// ---------------------------------------------------------------------------
enum { EPI_GELU = 1, EPI_BLEND = 2, EPI_F32 = 3, EPI_QKV = 4 };

template <int EPI>
__global__ __launch_bounds__(256, 3) void gemm_kernel(
    const unsigned short* __restrict__ A, int lda,
    const unsigned short* __restrict__ Bt, int ldb,
    const float* __restrict__ bias,
    void* __restrict__ Cv, int ldc, int K,
    const float* __restrict__ hb, const float* __restrict__ xb,
    int swzn, int ntn)
{
    __shared__ unsigned short Alds[2][128 * 32];
    __shared__ unsigned short Blds[2][128 * 32];

    const int tid = threadIdx.x;
    const int lane = tid & 63;
    const int w = tid >> 6;
    const int wr = w >> 1, wc = w & 1;
    int mt, nt;
    if (swzn > 0) {
        const int xcd = (int)blockIdx.x & 7, seq = (int)blockIdx.x >> 3;
        nt = xcd * swzn + seq % swzn;
        mt = seq / swzn;
    } else {
        nt = (int)blockIdx.x % ntn;
        mt = (int)blockIdx.x / ntn;
    }
    const int m0 = mt * 128, n0 = nt * 128;
    const int lrow = lane & 15, lko = (lane >> 4) * 8;

    const int grow = w * 32 + (lane >> 2);
    const int gk8 = (lane & 3) * 8;
    const unsigned short* ga0 = A + (size_t)(m0 + grow) * lda + gk8;
    const unsigned short* ga1 = ga0 + (size_t)16 * lda;
    const unsigned short* gb0 = Bt + (size_t)(n0 + grow) * ldb + gk8;
    const unsigned short* gb1 = gb0 + (size_t)16 * ldb;

    auto stage = [&](int buf, int k0) {
        unsigned short* la = &Alds[buf][w * 1024];
        unsigned short* lb = &Blds[buf][w * 1024];
        gload16(ga0 + k0, la);
        gload16(ga1 + k0, la + 512);
        gload16(gb0 + k0, lb);
        gload16(gb1 + k0, lb + 512);
    };

    f32x4 acc[4][4];
#pragma unroll
    for (int i = 0; i < 4; ++i)
#pragma unroll
        for (int j = 0; j < 4; ++j) acc[i][j] = (f32x4){0.f, 0.f, 0.f, 0.f};

    const int kks = K >> 5;
    stage(0, 0);
    __syncthreads();

    for (int t = 0; t < kks; ++t) {
        const int cur = t & 1;
        if (t + 1 < kks) stage(cur ^ 1, (t + 1) << 5);   // overlap with compute

        s16x8 af[4], bfr[4];
#pragma unroll
        for (int mi = 0; mi < 4; ++mi)
            af[mi] = *reinterpret_cast<const s16x8*>(&Alds[cur][(wr * 64 + mi * 16 + lrow) * 32 + lko]);
#pragma unroll
        for (int ni = 0; ni < 4; ++ni)
            bfr[ni] = *reinterpret_cast<const s16x8*>(&Blds[cur][(wc * 64 + ni * 16 + lrow) * 32 + lko]);
#pragma unroll
        for (int mi = 0; mi < 4; ++mi)
#pragma unroll
            for (int ni = 0; ni < 4; ++ni)
                acc[mi][ni] = __builtin_amdgcn_mfma_f32_16x16x32_bf16(af[mi], bfr[ni], acc[mi][ni], 0, 0, 0);

        __syncthreads();
    }

    const int rbase = m0 + wr * 64;
    const int cbase = n0 + wc * 64;
#pragma unroll
    for (int mi = 0; mi < 4; ++mi) {
#pragma unroll
        for (int j = 0; j < 4; ++j) {
            const int r = rbase + mi * 16 + (lane >> 4) * 4 + j;
#pragma unroll
            for (int ni = 0; ni < 4; ++ni) {
                const int c = cbase + ni * 16 + (lane & 15);
                float v = acc[mi][ni][j] + bias[c];
                if constexpr (EPI == EPI_GELU) {
                    float g = 0.5f * v * (1.f + erff(v * 0.70710678118654752f));
                    ((unsigned short*)Cv)[(size_t)r * ldc + c] = f2bf(g);
                } else if constexpr (EPI == EPI_BLEND) {
                    float gate = 1.f / (1.f + __expf(-v));
                    const size_t o = (size_t)r * ldc + c;
                    float bl = gate * hb[o] + (1.f - gate) * xb[o];
                    ((unsigned short*)Cv)[o] = f2bf(bl);
                } else if constexpr (EPI == EPI_QKV) {
                    const float scl = (c < 1024) ? QSCALE : 1.f;
                    ((unsigned short*)Cv)[(size_t)r * ldc + c] = f2bf(v * scl);
                } else {
                    ((float*)Cv)[(size_t)r * ldc + c] = v;
                }
            }
        }
    }
}

// ---------------------------------------------------------------------------
// 64x64-tile GEMM, templated epilogue, 4 blocks/CU (for N=1024 layers:
// blend + out-proj; grid = 8*swzn*mtn with swzn=2 -> 1024 blocks).
// ---------------------------------------------------------------------------
template <int EPI>
__global__ __launch_bounds__(256, 4) void gemm64_kernel(
    const unsigned short* __restrict__ A, int lda,
    const unsigned short* __restrict__ Bt, int ldb,
    const float* __restrict__ bias,
    void* __restrict__ Cv, int ldc, int K,
    const float* __restrict__ hb, const float* __restrict__ xb,
    int swzn)
{
    __shared__ unsigned short Alds[2][64 * 32];
    __shared__ unsigned short Blds[2][64 * 32];

    const int tid = threadIdx.x;
    const int lane = tid & 63;
    const int w = tid >> 6;
    const int wr = w >> 1, wc = w & 1;
    const int xcd = (int)blockIdx.x & 7, seq = (int)blockIdx.x >> 3;
    const int nt = xcd * swzn + seq % swzn;
    const int mt = seq / swzn;
    const int m0 = mt * 64, n0 = nt * 64;
    const int lrow = lane & 15, lko = (lane >> 4) * 8;

    const int grow = w * 16 + (lane >> 2);
    const int gk8 = (lane & 3) * 8;
    const unsigned short* ga = A + (size_t)(m0 + grow) * lda + gk8;
    const unsigned short* gb = Bt + (size_t)(n0 + grow) * ldb + gk8;

    auto stage = [&](int buf, int k0) {
        gload16(ga + k0, &Alds[buf][w * 512]);
        gload16(gb + k0, &Blds[buf][w * 512]);
    };

    f32x4 acc[2][2];
#pragma unroll
    for (int i = 0; i < 2; ++i)
#pragma unroll
        for (int j = 0; j < 2; ++j) acc[i][j] = (f32x4){0.f, 0.f, 0.f, 0.f};

    const int kks = K >> 5;
    stage(0, 0);
    __syncthreads();

    for (int t = 0; t < kks; ++t) {
        const int cur = t & 1;
        if (t + 1 < kks) stage(cur ^ 1, (t + 1) << 5);

        s16x8 af[2], bfr[2];
#pragma unroll
        for (int mi = 0; mi < 2; ++mi)
            af[mi] = *reinterpret_cast<const s16x8*>(&Alds[cur][(wr * 32 + mi * 16 + lrow) * 32 + lko]);
#pragma unroll
        for (int ni = 0; ni < 2; ++ni)
            bfr[ni] = *reinterpret_cast<const s16x8*>(&Blds[cur][(wc * 32 + ni * 16 + lrow) * 32 + lko]);
#pragma unroll
        for (int mi = 0; mi < 2; ++mi)
#pragma unroll
            for (int ni = 0; ni < 2; ++ni)
                acc[mi][ni] = __builtin_amdgcn_mfma_f32_16x16x32_bf16(af[mi], bfr[ni], acc[mi][ni], 0, 0, 0);

        __syncthreads();
    }

    const int rbase = m0 + wr * 32;
    const int cbase = n0 + wc * 32;
#pragma unroll
    for (int mi = 0; mi < 2; ++mi) {
#pragma unroll
        for (int j = 0; j < 4; ++j) {
            const int r = rbase + mi * 16 + (lane >> 4) * 4 + j;
#pragma unroll
            for (int ni = 0; ni < 2; ++ni) {
                const int c = cbase + ni * 16 + (lane & 15);
                float v = acc[mi][ni][j] + bias[c];
                if constexpr (EPI == EPI_BLEND) {
                    float gate = 1.f / (1.f + __expf(-v));
                    const size_t o = (size_t)r * ldc + c;
                    float bl = gate * hb[o] + (1.f - gate) * xb[o];
                    ((unsigned short*)Cv)[o] = f2bf(bl);
                } else {
                    ((float*)Cv)[(size_t)r * ldc + c] = v;
                }
            }
        }
    }
}

// ---------------------------------------------------------------------------
// Gate-1 split-K partial GEMM: partial[ks] = hx[:, ks*512:+512] @ Wg1-slice.
// BM=32, BN=256 (full N -> A read ONCE), KS=4; grid = 512 = 2 blocks/CU.
// ---------------------------------------------------------------------------
__global__ __launch_bounds__(256, 4) void gelu_partial(
    const float* __restrict__ h, const float* __restrict__ x,
    const unsigned short* __restrict__ Bt,   // wg1T [256][2048]
    float* __restrict__ partial)             // [4][4096][256]
{
    __shared__ unsigned short Alds[2][32 * 32];
    __shared__ unsigned short Blds[2][256 * 32];

    const int tid = threadIdx.x;
    const int lane = tid & 63;
    const int w = tid >> 6;
    const int mt = (int)blockIdx.x >> 2, ks = (int)blockIdx.x & 3;
    const int m0 = mt * 32, kbase = ks * 512;
    const int lrow = lane & 15, lko = (lane >> 4) * 8;

    const int arl = tid >> 3, ac4 = (tid & 7) * 4;
    const size_t arg = (size_t)(m0 + arl) * 1024;
    auto loadA = [&](int k0, f32x4& v) {
        v = *reinterpret_cast<const f32x4*>((k0 < 1024 ? h : x) + arg + (k0 & 1023) + ac4);
    };
    auto writeA = [&](int buf, const f32x4& v) {
        u32x2 p = {pack2bf(v[0], v[1]), pack2bf(v[2], v[3])};
        *reinterpret_cast<u32x2*>(&Alds[buf][arl * 32 + ac4]) = p;
    };

    const int brow = w * 64 + (lane >> 2);
    const int bk8 = (lane & 3) * 8;
    const unsigned short* gb = Bt + (size_t)brow * 2048 + kbase + bk8;
    auto stageB = [&](int buf, int k0) {
#pragma unroll
        for (int i = 0; i < 4; ++i)
            gload16(gb + (size_t)(i * 16) * 2048 + k0, &Blds[buf][(w * 64 + i * 16) * 32]);
    };

    f32x4 acc[2][4];
#pragma unroll
    for (int i = 0; i < 2; ++i)
#pragma unroll
        for (int j = 0; j < 4; ++j) acc[i][j] = (f32x4){0.f, 0.f, 0.f, 0.f};

    f32x4 areg;
    loadA(kbase, areg);
    stageB(0, 0);
    writeA(0, areg);
    __syncthreads();

    for (int t = 0; t < 16; ++t) {
        const int cur = t & 1;
        if (t + 1 < 16) {
            loadA(kbase + ((t + 1) << 5), areg);   // issue early (T14)
            stageB(cur ^ 1, (t + 1) << 5);
        }

        s16x8 af[2], bfr[4];
#pragma unroll
        for (int mi = 0; mi < 2; ++mi)
            af[mi] = *reinterpret_cast<const s16x8*>(&Alds[cur][(mi * 16 + lrow) * 32 + lko]);
#pragma unroll
        for (int ni = 0; ni < 4; ++ni)
            bfr[ni] = *reinterpret_cast<const s16x8*>(&Blds[cur][(w * 64 + ni * 16 + lrow) * 32 + lko]);
#pragma unroll
        for (int mi = 0; mi < 2; ++mi)
#pragma unroll
            for (int ni = 0; ni < 4; ++ni)
                acc[mi][ni] = __builtin_amdgcn_mfma_f32_16x16x32_bf16(af[mi], bfr[ni], acc[mi][ni], 0, 0, 0);

        if (t + 1 < 16) writeA(cur ^ 1, areg);     // write late (T14)
        __syncthreads();
    }

    float* pbase = partial + (size_t)ks * 4096 * 256;
#pragma unroll
    for (int mi = 0; mi < 2; ++mi) {
#pragma unroll
        for (int j = 0; j < 4; ++j) {
            const int r = m0 + mi * 16 + (lane >> 4) * 4 + j;
#pragma unroll
            for (int ni = 0; ni < 4; ++ni) {
                const int c = w * 64 + ni * 16 + (lane & 15);
                pbase[(size_t)r * 256 + c] = acc[mi][ni][j];
            }
        }
    }
}

// ---------------------------------------------------------------------------
// Gate-1 reduce: g1 = bf16(gelu(sum_ks partial + bias)). 4 elems/thread.
// ---------------------------------------------------------------------------
__global__ __launch_bounds__(256) void gelu_reduce(
    const float* __restrict__ partial, const float* __restrict__ bias,
    unsigned short* __restrict__ g1)
{
    const size_t idx = ((size_t)blockIdx.x * 256 + threadIdx.x) * 4;
    const int c = (int)(idx & 255);
    f32x4 s = *reinterpret_cast<const f32x4*>(partial + idx);
#pragma unroll
    for (int ks = 1; ks < 4; ++ks) {
        f32x4 p = *reinterpret_cast<const f32x4*>(partial + (size_t)ks * 4096 * 256 + idx);
        s[0] += p[0]; s[1] += p[1]; s[2] += p[2]; s[3] += p[3];
    }
    f32x4 bb = *reinterpret_cast<const f32x4*>(bias + c);
    u16x4 o;
#pragma unroll
    for (int j = 0; j < 4; ++j) {
        float v = s[j] + bb[j];
        o[j] = f2bf(0.5f * v * (1.f + erff(v * 0.70710678118654752f)));
    }
    *reinterpret_cast<u16x4*>(g1 + idx) = o;
}

// ---------------------------------------------------------------------------
// Flash attention (round-18 proven): swapped-operand, QBLK=128, 4 waves x 32
// q-rows, grid 512. K/V via global_load_lds with both-sides XOR chunk-swizzle:
//   LDS[R][C] = orig[R][C ^ (R&7)]  (C = 16B chunk index 0..7)
// FULLY ROTATED PV: both PV clusters of tile t execute at the TOP of
// iteration t+1 (vf registers + P0/P1 in separate wave-private LDS regions
// survive the barrier; lgkm already drained). -M folded into the QK
// accumulator init. setprio(1) around MFMA clusters. FIXED-M softmax.
//   qkv: [4096][3072] bf16 (q pre-scaled by 0.125*log2e | k | v)
//   vt : [32 bh][64 d][2048 s] bf16
//   out: [4096][1024] bf16
// 1D XCD-grouped grid: 512 blocks = 8 xcd x (4 bh x 16 qt).
// ---------------------------------------------------------------------------
#define ALD 72   // Plds row stride only

__global__ __launch_bounds__(256, 3) void attn_kernel(
    const unsigned short* __restrict__ qkv,
    const unsigned short* __restrict__ vt,
    unsigned short* __restrict__ out)
{
    __shared__ unsigned short Klds[2][64 * 64];   // linear 128B rows
    __shared__ unsigned short Vlds[2][64 * 64];
    __shared__ unsigned short Plds[2][4][16 * ALD];   // [P-group][wave]

    const int tid = threadIdx.x, lane = tid & 63, w = tid >> 6;   // w 0..3
    const int xcd = (int)blockIdx.x & 7, seq = (int)blockIdx.x >> 3;  // 512 = 8*64
    const int bh = xcd * 4 + (seq & 3);   // 4 heads per XCD
    const int qt = seq >> 2;              // 0..15
    const int b = bh >> 4, h = bh & 15;
    const int rb = b * 2048;
    const int lrow = lane & 15, g = lane >> 4, lko = g * 8;

    s16x8 qf[2][2];
#pragma unroll
    for (int qg = 0; qg < 2; ++qg) {
        const size_t qrow = (size_t)(rb + qt * 128 + w * 32 + qg * 16 + lrow) * 3072 + h * 64;
        qf[qg][0] = *reinterpret_cast<const s16x8*>(qkv + qrow + lko);
        qf[qg][1] = *reinterpret_cast<const s16x8*>(qkv + qrow + 32 + lko);
    }

    const int grow = w * 16 + (lane >> 3);
    const int gswz = ((lane & 7) ^ (lane >> 3)) * 8;   // elems
    const unsigned short* kgp = qkv + (size_t)(rb + grow) * 3072 + 1024 + h * 64 + gswz;
    const unsigned short* vgp = vt + (size_t)(bh * 64 + grow) * 2048 + gswz;

    auto stage = [&](int buf, int t0) {
        gload16(kgp + (size_t)t0 * 3072, &Klds[buf][w * 1024]);
        gload16(kgp + (size_t)(t0 + 8) * 3072, &Klds[buf][w * 1024 + 512]);
        gload16(vgp + t0, &Vlds[buf][w * 1024]);
        gload16(vgp + t0 + 8 * 2048, &Vlds[buf][w * 1024 + 512]);
    };

    const int cs0 = ((g) ^ (lrow & 7)) * 8;
    const int cs1 = ((4 + g) ^ (lrow & 7)) * 8;

    f32x4 acc0[4], acc1[4];
#pragma unroll
    for (int di = 0; di < 4; ++di) {
        acc0[di] = (f32x4){0.f, 0.f, 0.f, 0.f};
        acc1[di] = (f32x4){0.f, 0.f, 0.f, 0.f};
    }
    float lsum0 = 0.f, lsum1 = 0.f;

    unsigned short* pw0 = &Plds[0][w][0];
    unsigned short* pw1 = &Plds[1][w][0];
    s16x8 vf[2][4];   // persists across iterations (PV rotation)

    stage(0, 0);
    __syncthreads();

    for (int t0 = 0; t0 < 2048; t0 += 64) {
        const int cur = (t0 >> 6) & 1;
        if (t0 + 64 < 2048) stage(cur ^ 1, t0 + 64);

        // PV of PREVIOUS tile (both groups): vf regs + wave-private P0/P1;
        // lgkm drained by the barrier -> 32 back-to-back MFMAs.
        if (t0 > 0) {
            __builtin_amdgcn_s_setprio(1);
#pragma unroll
            for (int st = 0; st < 2; ++st) {
                s16x8 pf0 = *reinterpret_cast<const s16x8*>(&pw0[lrow * ALD + st * 32 + lko]);
#pragma unroll
                for (int di = 0; di < 4; ++di)
                    acc0[di] = __builtin_amdgcn_mfma_f32_16x16x32_bf16(vf[st][di], pf0, acc0[di], 0, 0, 0);
            }
#pragma unroll
            for (int st = 0; st < 2; ++st) {
                s16x8 pf1 = *reinterpret_cast<const s16x8*>(&pw1[lrow * ALD + st * 32 + lko]);
#pragma unroll
                for (int di = 0; di < 4; ++di)
                    acc1[di] = __builtin_amdgcn_mfma_f32_16x16x32_bf16(vf[st][di], pf1, acc1[di], 0, 0, 0);
            }
            __builtin_amdgcn_s_setprio(0);
        }

        s16x8 kf[4][2];
#pragma unroll
        for (int ni = 0; ni < 4; ++ni) {
            kf[ni][0] = *reinterpret_cast<const s16x8*>(&Klds[cur][(ni * 16 + lrow) * 64 + cs0]);
            kf[ni][1] = *reinterpret_cast<const s16x8*>(&Klds[cur][(ni * 16 + lrow) * 64 + cs1]);
        }

        // QK group 0 (accumulator pre-seeded with -M: s = QK - M)
        f32x4 s0[4];
#pragma unroll
        for (int ni = 0; ni < 4; ++ni)
            s0[ni] = (f32x4){-FIXED_M, -FIXED_M, -FIXED_M, -FIXED_M};
        __builtin_amdgcn_s_setprio(1);
#pragma unroll
        for (int ni = 0; ni < 4; ++ni)
#pragma unroll
            for (int fi = 0; fi < 2; ++fi)
                s0[ni] = __builtin_amdgcn_mfma_f32_16x16x32_bf16(kf[ni][fi], qf[0][fi], s0[ni], 0, 0, 0);
        __builtin_amdgcn_s_setprio(0);

        // P0 = exp2(s0) -> pw0 (consumed next iteration)
#pragma unroll
        for (int ni = 0; ni < 4; ++ni) {
            float p0 = __builtin_amdgcn_exp2f(s0[ni][0]);
            float p1 = __builtin_amdgcn_exp2f(s0[ni][1]);
            float p2 = __builtin_amdgcn_exp2f(s0[ni][2]);
            float p3 = __builtin_amdgcn_exp2f(s0[ni][3]);
            lsum0 += (p0 + p1) + (p2 + p3);
            u32x2 pk = {pack2bf(p0, p1), pack2bf(p2, p3)};
            *reinterpret_cast<u32x2*>(&pw0[lrow * ALD + ni * 16 + g * 4]) = pk;
        }

        // QK group 1 (kf reused from registers)
        f32x4 s1[4];
#pragma unroll
        for (int ni = 0; ni < 4; ++ni)
            s1[ni] = (f32x4){-FIXED_M, -FIXED_M, -FIXED_M, -FIXED_M};
        __builtin_amdgcn_s_setprio(1);
#pragma unroll
        for (int ni = 0; ni < 4; ++ni)
#pragma unroll
            for (int fi = 0; fi < 2; ++fi)
                s1[ni] = __builtin_amdgcn_mfma_f32_16x16x32_bf16(kf[ni][fi], qf[1][fi], s1[ni], 0, 0, 0);
        __builtin_amdgcn_s_setprio(0);

        // V fragments for NEXT iteration's PV (prev vf consumed above)
#pragma unroll
        for (int di = 0; di < 4; ++di) {
            vf[0][di] = *reinterpret_cast<const s16x8*>(&Vlds[cur][(di * 16 + lrow) * 64 + cs0]);
            vf[1][di] = *reinterpret_cast<const s16x8*>(&Vlds[cur][(di * 16 + lrow) * 64 + cs1]);
        }

        // P1 = exp2(s1) -> pw1 (consumed next iteration)
#pragma unroll
        for (int ni = 0; ni < 4; ++ni) {
            float p0 = __builtin_amdgcn_exp2f(s1[ni][0]);
            float p1 = __builtin_amdgcn_exp2f(s1[ni][1]);
            float p2 = __builtin_amdgcn_exp2f(s1[ni][2]);
            float p3 = __builtin_amdgcn_exp2f(s1[ni][3]);
            lsum1 += (p0 + p1) + (p2 + p3);
            u32x2 pk = {pack2bf(p0, p1), pack2bf(p2, p3)};
            *reinterpret_cast<u32x2*>(&pw1[lrow * ALD + ni * 16 + g * 4]) = pk;
        }

        __syncthreads();   // drains gload vmcnt + lgkm (P writes) for next iter
    }

    // tail: PV of the last tile (both groups)
#pragma unroll
    for (int st = 0; st < 2; ++st) {
        s16x8 pf0 = *reinterpret_cast<const s16x8*>(&pw0[lrow * ALD + st * 32 + lko]);
#pragma unroll
        for (int di = 0; di < 4; ++di)
            acc0[di] = __builtin_amdgcn_mfma_f32_16x16x32_bf16(vf[st][di], pf0, acc0[di], 0, 0, 0);
    }
#pragma unroll
    for (int st = 0; st < 2; ++st) {
        s16x8 pf1 = *reinterpret_cast<const s16x8*>(&pw1[lrow * ALD + st * 32 + lko]);
#pragma unroll
        for (int di = 0; di < 4; ++di)
            acc1[di] = __builtin_amdgcn_mfma_f32_16x16x32_bf16(vf[st][di], pf1, acc1[di], 0, 0, 0);
    }

    lsum0 += __shfl_xor(lsum0, 16);
    lsum0 += __shfl_xor(lsum0, 32);
    lsum1 += __shfl_xor(lsum1, 16);
    lsum1 += __shfl_xor(lsum1, 32);
    const float inv0 = 1.f / lsum0;
    const float inv1 = 1.f / lsum1;
    const size_t orow0 = (size_t)(rb + qt * 128 + w * 32 + lrow) * 1024 + h * 64;
    const size_t orow1 = orow0 + (size_t)16 * 1024;
#pragma unroll
    for (int di = 0; di < 4; ++di) {
        u32x2 ov0 = {pack2bf(acc0[di][0] * inv0, acc0[di][1] * inv0),
                     pack2bf(acc0[di][2] * inv0, acc0[di][3] * inv0)};
        *reinterpret_cast<u32x2*>(&out[orow0 + di * 16 + g * 4]) = ov0;
        u32x2 ov1 = {pack2bf(acc1[di][0] * inv1, acc1[di][1] * inv1),
                     pack2bf(acc1[di][2] * inv1, acc1[di][3] * inv1)};
        *reinterpret_cast<u32x2*>(&out[orow1 + di * 16 + g * 4]) = ov1;
    }
}

// ---------------------------------------------------------------------------
extern "C" void kernel_launch(void* const* d_in, const int* in_sizes, int n_in,
                              void* d_out, int out_size, void* d_ws, size_t ws_size,
                              hipStream_t stream)
{
    const float* h   = (const float*)d_in[0];
    const float* x   = (const float*)d_in[1];
    const float* Wq  = (const float*)d_in[2];
    const float* bq  = (const float*)d_in[3];
    const float* Wk  = (const float*)d_in[4];
    const float* bk  = (const float*)d_in[5];
    const float* Wv  = (const float*)d_in[6];
    const float* bv  = (const float*)d_in[7];
    const float* Wo  = (const float*)d_in[8];
    const float* bo  = (const float*)d_in[9];
    const float* Wg1 = (const float*)d_in[10];
    const float* bg1 = (const float*)d_in[11];
    const float* Wg2 = (const float*)d_in[12];
    const float* bg2 = (const float*)d_in[13];

    char* ws = (char*)d_ws;
    size_t off = 0;
    auto alloc = [&](size_t bytes) {
        void* p = ws + off;
        off += (bytes + 255) & ~(size_t)255;
        return p;
    };
    unsigned short* wg1T  = (unsigned short*)alloc((size_t)256 * 2048 * 2);
    unsigned short* wg2T  = (unsigned short*)alloc((size_t)1024 * 256 * 2);
    unsigned short* wqkvT = (unsigned short*)alloc((size_t)3072 * 1024 * 2);
    unsigned short* woT   = (unsigned short*)alloc((size_t)1024 * 1024 * 2);
    float*          bqkv  = (float*)alloc((size_t)3072 * 4);
    unsigned short* blend = (unsigned short*)alloc((size_t)4096 * 1024 * 2);
    unsigned short* attno = (unsigned short*)alloc((size_t)4096 * 1024 * 2);
    unsigned short* vtb   = (unsigned short*)alloc((size_t)32 * 64 * 2048 * 2);
    unsigned short* g1    = (unsigned short*)alloc((size_t)4096 * 256 * 2);
    unsigned short* qkv   = (unsigned short*)alloc((size_t)4096 * 3072 * 2);
    // gate-1 split-K partials (16 MB fp32) alias the qkv buffer (24 MB):
    // partials are dead before the QKV GEMM writes qkv.
    float* partial = (float*)qkv;
    (void)ws_size; (void)in_sizes; (void)n_in; (void)out_size;

    // fused prep: weight transposes + bias concat (one launch)
    TTable tt;
    tt.e[0] = {Wg1, wg1T, 2048, 256};
    tt.e[1] = {Wg2, wg2T, 256, 1024};
    tt.e[2] = {Wq, wqkvT, 1024, 1024};
    tt.e[3] = {Wk, wqkvT + (size_t)1024 * 1024, 1024, 1024};
    tt.e[4] = {Wv, wqkvT + (size_t)2048 * 1024, 1024, 1024};
    tt.e[5] = {Wo, woT, 1024, 1024};
    prep_all<<<3072 + 12, 256, 0, stream>>>(tt, bq, bk, bv, bqkv);

    // gate MLP: split-K gate1 (A read once, 512 blocks) + reduce/GELU
    gelu_partial<<<512, 256, 0, stream>>>(h, x, wg1T, partial);
    gelu_reduce<<<1024, 256, 0, stream>>>(partial, bg1, g1);
    // blend: 64x64 tiles, 1024 blocks = 4 blocks/CU
    gemm64_kernel<EPI_BLEND><<<1024, 256, 0, stream>>>(
        g1, 256, wg2T, 256, bg2, blend, 1024, 256, h, x, 2);

    // QKV (packed, N = 3072; q pre-scaled) — overwrites partial (dead)
    gemm_kernel<EPI_QKV><<<768, 256, 0, stream>>>(
        blend, 1024, wqkvT, 1024, bqkv, qkv, 3072, 1024, nullptr, nullptr, 3, 24);

    // V -> per-head transposed
    transpose_v<<<dim3(32, 32), 256, 0, stream>>>(qkv, vtb);

    // attention (XCD-grouped 1D grid, QBLK=128, fully-rotated PV pipeline)
    attn_kernel<<<512, 256, 0, stream>>>(qkv, vtb, attno);

    // output projection -> fp32: 64x64 tiles, 1024 blocks = 4 blocks/CU
    gemm64_kernel<EPI_F32><<<1024, 256, 0, stream>>>(
        attno, 1024, woT, 1024, bo, (float*)d_out, 1024, 1024, nullptr, nullptr, 2);
}